// Round 1
// baseline (185.705 us; speedup 1.0000x reference)
//
#include <hip/hip_runtime.h>

#define LL 16
#define CC 32
#define HIDN 16
#define HH 64
#define WW 64
#define HW 4096  // 64*64

// ---------------- cumsum of flows over L ----------------
// flows layout: (1, L, 2, H, W) -> flows[l*2*HW + p*HW + pix]
__global__ __launch_bounds__(256) void cumsum_kernel(const float* __restrict__ flows,
                                                     float* __restrict__ cum) {
    int idx = blockIdx.x * 256 + threadIdx.x;   // 0 .. 2*HW-1  (p*HW + pix)
    float acc = 0.0f;
#pragma unroll
    for (int l = 0; l < LL; ++l) {
        acc += flows[l * 2 * HW + idx];
        cum[l * 2 * HW + idx] = acc;
    }
}

// ---------------- main fused kernel ----------------
// grid: (tiles=16, k=16, t=16), block 256 threads = 256 pixels (4 rows of 64)
__global__ __launch_bounds__(256) void gsp_kernel(const float* __restrict__ images,
                                                  const float* __restrict__ cum,
                                                  const float* __restrict__ w1,
                                                  const float* __restrict__ b1,
                                                  const float* __restrict__ w2,
                                                  const float* __restrict__ b2,
                                                  const float* __restrict__ decay_log,
                                                  float* __restrict__ out) {
    const int tile = blockIdx.x;
    const int k    = blockIdx.y;
    const int t    = blockIdx.z;
    if (k > t) return;   // zero weight; whole block exits uniformly

    __shared__ float w1s[HIDN * 2 * CC];  // 1024
    __shared__ float w2s[2 * HIDN];       // 32
    __shared__ float b1s[HIDN];
    __shared__ float b2s[2];

    const int tid = threadIdx.x;
    // stage weights in LDS (broadcast reads later -> conflict-free)
    {
        float4 v = ((const float4*)w1)[tid];          // 256*4 = 1024 floats
        ((float4*)w1s)[tid] = v;
        if (tid < HIDN) b1s[tid] = b1[tid];
        if (tid < 2 * HIDN) w2s[tid] = w2[tid];
        if (tid < 2) b2s[tid] = b2[tid];
    }
    __syncthreads();

    const int pix = tile * 256 + tid;      // 0..4095
    const int wx = pix & 63;
    const int hy = pix >> 6;

    const float* imgT = images + (size_t)t * CC * HW;   // frame t base
    const float* imgK = images + (size_t)k * CC * HW;   // frame k base

    // ---- MLP: h = relu(W1 * [img_t; img_k] + b1) ----
    float hacc[HIDN];
#pragma unroll
    for (int o = 0; o < HIDN; ++o) hacc[o] = b1s[o];

#pragma unroll 8
    for (int c = 0; c < CC; ++c) {
        float v = imgT[c * HW + pix];
#pragma unroll
        for (int o = 0; o < HIDN; ++o)
            hacc[o] = fmaf(w1s[o * 64 + c], v, hacc[o]);
    }
#pragma unroll 8
    for (int c = 0; c < CC; ++c) {
        float v = imgK[c * HW + pix];
#pragma unroll
        for (int o = 0; o < HIDN; ++o)
            hacc[o] = fmaf(w1s[o * 64 + 32 + c], v, hacc[o]);
    }

    float res0 = b2s[0], res1 = b2s[1];
#pragma unroll
    for (int o = 0; o < HIDN; ++o) {
        float ho = fmaxf(hacc[o], 0.0f);
        res0 = fmaf(w2s[o], ho, res0);
        res1 = fmaf(w2s[HIDN + o], ho, res1);
    }

    // ---- relative displacement + residual ----
    float relx = cum[t * 2 * HW + pix] - cum[k * 2 * HW + pix] + res0;
    float rely = cum[t * 2 * HW + HW + pix] - cum[k * 2 * HW + HW + pix] + res1;

    // base grid: linspace(-1+1/N, 1-1/N, N) -> (2*i+1)/N - 1
    float gx = ((float)(2 * wx + 1) / 64.0f - 1.0f) + relx;
    float gy = ((float)(2 * hy + 1) / 64.0f - 1.0f) + rely;

    // wrap x: mod(gx+1, 2) - 1  (floor-mod, matching jnp.mod)
    float xp = gx + 1.0f;
    xp = xp - floorf(xp * 0.5f) * 2.0f;
    float gxw = xp - 1.0f;

    float ix = ((gxw + 1.0f) * 64.0f - 1.0f) * 0.5f;
    float iy = ((gy  + 1.0f) * 64.0f - 1.0f) * 0.5f;

    float ix0f = floorf(ix), iy0f = floorf(iy);
    float wx1 = ix - ix0f, wy1 = iy - iy0f;
    float wx0 = 1.0f - wx1, wy0 = 1.0f - wy1;
    int ix0 = (int)ix0f, iy0 = (int)iy0f;
    int ix1 = ix0 + 1,   iy1 = iy0 + 1;

    float cwt[4];
    int   off[4];
    {
        int xi[4] = {ix0, ix1, ix0, ix1};
        int yi[4] = {iy0, iy0, iy1, iy1};
        float ww[4] = {wx0 * wy0, wx1 * wy0, wx0 * wy1, wx1 * wy1};
#pragma unroll
        for (int j = 0; j < 4; ++j) {
            bool valid = (xi[j] >= 0) & (xi[j] < WW) & (yi[j] >= 0) & (yi[j] < HH);
            int xc = min(max(xi[j], 0), WW - 1);
            int yc = min(max(yi[j], 0), HH - 1);
            off[j] = yc * WW + xc;
            cwt[j] = valid ? ww[j] : 0.0f;
        }
    }

    // decay weight
    float lam = expf(decay_log[0]);
    float wt = expf(-lam * (float)(t - k));

    float* outT = out + (size_t)t * CC * HW + pix;
    const float w0 = cwt[0] * wt, w1c = cwt[1] * wt, w2c = cwt[2] * wt, w3 = cwt[3] * wt;

#pragma unroll 8
    for (int c = 0; c < CC; ++c) {
        const float* pl = imgK + c * HW;
        float v = w0 * pl[off[0]] + w1c * pl[off[1]] + w2c * pl[off[2]] + w3 * pl[off[3]];
        atomicAdd(outT + c * HW, v);
    }
}

extern "C" void kernel_launch(void* const* d_in, const int* in_sizes, int n_in,
                              void* d_out, int out_size, void* d_ws, size_t ws_size,
                              hipStream_t stream) {
    const float* flows     = (const float*)d_in[0];  // (1,16,2,64,64)
    const float* images    = (const float*)d_in[1];  // (1,16,32,64,64)
    const float* decay_log = (const float*)d_in[2];  // scalar
    const float* w1        = (const float*)d_in[3];  // (16,64)
    const float* b1        = (const float*)d_in[4];  // (16,)
    const float* w2        = (const float*)d_in[5];  // (2,16)
    const float* b2        = (const float*)d_in[6];  // (2,)
    float* out = (float*)d_out;                      // (1,16,32,64,64)
    float* cum = (float*)d_ws;                       // L*2*HW floats = 512 KB

    // zero the output (harness poisons it with 0xAA before every launch)
    hipMemsetAsync(d_out, 0, (size_t)out_size * sizeof(float), stream);

    // cumsum of flows over L
    cumsum_kernel<<<dim3(2 * HW / 256), dim3(256), 0, stream>>>(flows, cum);

    // main fused kernel: grid (tile, k, t)
    gsp_kernel<<<dim3(16, 16, 16), dim3(256), 0, stream>>>(
        images, cum, w1, b1, w2, b2, decay_log, out);
}